// Round 1
// 148.960 us; speedup vs baseline: 1.0545x; 1.0545x over previous
//
#include <hip/hip_runtime.h>
#include <hip/hip_bf16.h>
#include <stdint.h>

#define PDIM 4096
#define KSEL 3687.0f
#define NITER 50

typedef unsigned short ushort_t;
typedef __attribute__((ext_vector_type(8))) __bf16 bf16x8;
typedef __attribute__((ext_vector_type(4))) float f32x4;

typedef __attribute__((address_space(3))) void lds_void;
typedef __attribute__((address_space(1))) const void glob_void;

__device__ __forceinline__ ushort_t f32_to_bf16_rne(float f) {
  union { float f; uint32_t u; } v; v.f = f;
  uint32_t r = 0x7FFFu + ((v.u >> 16) & 1u);
  return (ushort_t)((v.u + r) >> 16);
}

__device__ __forceinline__ float bf16_to_f32(ushort_t h) {
  union { uint32_t u; float f; } v; v.u = ((uint32_t)h) << 16;
  return v.f;
}

__device__ __forceinline__ void async_cp16(const void* g, void* l) {
  __builtin_amdgcn_global_load_lds((glob_void*)g, (lds_void*)l, 16, 0, 0);
}

// Canonical CDNA wave64 sum via DPP (row_shr 1/2/4/8 + row_bcast 15/31).
// Result lands in lane 63. ~6 VALU-latency ops vs ~200cy of ds_bpermute chain.
__device__ __forceinline__ float wave_sum_dpp(float x) {
  float s = x;
  int t;
  t = __builtin_amdgcn_update_dpp(0, __float_as_int(s), 0x111, 0xF, 0xF, true);
  s += __int_as_float(t);  // row_shr:1
  t = __builtin_amdgcn_update_dpp(0, __float_as_int(s), 0x112, 0xF, 0xF, true);
  s += __int_as_float(t);  // row_shr:2
  t = __builtin_amdgcn_update_dpp(0, __float_as_int(s), 0x114, 0xF, 0xF, true);
  s += __int_as_float(t);  // row_shr:4
  t = __builtin_amdgcn_update_dpp(0, __float_as_int(s), 0x118, 0xF, 0xF, true);
  s += __int_as_float(t);  // row_shr:8 -> lane15/31/47/63 hold row sums
  t = __builtin_amdgcn_update_dpp(0, __float_as_int(s), 0x142, 0xA, 0xF, true);
  s += __int_as_float(t);  // row_bcast:15 -> lane31 = rows0+1, lane63 = rows2+3
  t = __builtin_amdgcn_update_dpp(0, __float_as_int(s), 0x143, 0xC, 0xF, true);
  s += __int_as_float(t);  // row_bcast:31 -> lane63 = all 64
  return s;
}

// ---------------- Kernel 1: fused Dykstra (block 0) + V->LLC prefetch
// (blocks 1..2048) + x->bf16 (blocks 2049..). The V prefetch streams 64 MiB
// into Infinity Cache under the ~13us serial-Dykstra shadow so wmat's read
// side becomes LLC-resident instead of HBM-bound.
__global__ __launch_bounds__(256) void prep_kernel(
    const float* __restrict__ alpha, float* __restrict__ a_out,
    const float* __restrict__ x, ushort_t* __restrict__ Xb, int n4,
    const float* __restrict__ V) {
  if (blockIdx.x >= 1 && blockIdx.x <= 2048) {
    // V prefetch: 2048 blocks x 256 threads x 8 float4 = 64 MiB.
    const float4* V4 = (const float4*)V;
    const int base = (blockIdx.x - 1) * 2048 + (int)threadIdx.x;
#pragma unroll
    for (int i = 0; i < 8; ++i) {
      const float4 vv = V4[base + i * 256];
      // keep-alive: prevent DCE of the fill-only loads (guide rule #17)
      asm volatile("" :: "v"(vv.x), "v"(vv.y), "v"(vv.z), "v"(vv.w));
    }
    return;
  }
  if (blockIdx.x != 0) {
    const int i = (blockIdx.x - 2049) * 256 + threadIdx.x;
    if (i < n4) {
      const float4 v = ((const float4*)x)[i];
      ushort4 o;
      o.x = f32_to_bf16_rne(v.x);
      o.y = f32_to_bf16_rne(v.y);
      o.z = f32_to_bf16_rne(v.z);
      o.w = f32_to_bf16_rne(v.w);
      ((ushort4*)Xb)[i] = o;
    }
    return;
  }
  __shared__ float red[8];
  const int tid = threadIdx.x;
  const int lane = tid & 63;
  const int wv = tid >> 6;
  float xx[16], q[16];
  float p = 0.0f;
#pragma unroll
  for (int i = 0; i < 16; ++i) {
    xx[i] = alpha[i * 256 + tid] * 100.0f;  // s = alpha / 0.01
    q[i] = 0.0f;
  }
  for (int it = 0; it < NITER; ++it) {
    float t[16];
    float loc = 0.0f;
#pragma unroll
    for (int i = 0; i < 16; ++i) { t[i] = xx[i] + p; loc += t[i]; }
    loc = wave_sum_dpp(loc);
    const int slot = (it & 1) * 4;
    if (lane == 63) red[slot + wv] = loc;
    __syncthreads();
    const float tot = red[slot] + red[slot + 1] + red[slot + 2] + red[slot + 3];
    const float corr = (KSEL - tot) * (1.0f / 4096.0f);
    p = -corr;
#pragma unroll
    for (int i = 0; i < 16; ++i) {
      const float y = t[i] + corr;
      const float u = y + q[i];
      const float xn = fminf(fmaxf(u, 0.0f), 1.0f);
      q[i] = u - xn;
      xx[i] = xn;
    }
  }
#pragma unroll
  for (int i = 0; i < 16; ++i) a_out[i * 256 + tid] = xx[i];
}

// ---------------- Kernel 2: materialize W (row-major bf16) ----------------
// R3-proven config: 128x64 tile, 192-row fp32 V band in LDS, pad 67,
// phase-2 stores 128B-per-row segments. V reads now LLC-hit (prep prefetch).
__global__ __launch_bounds__(256) void wmat_kernel(
    const float* __restrict__ V, const float* __restrict__ a,
    ushort_t* __restrict__ Wb) {
  __shared__ float vt[192][67];
  const int t = threadIdx.x;
  const int r0 = blockIdx.x * 128;
  const int c0 = blockIdx.y * 64;
  const int dbase = (r0 - c0 - 63 + 2 * PDIM) & (PDIM - 1);
  const int csub = (t & 15) * 4;
  const int rsub = t >> 4;
#pragma unroll
  for (int i = 0; i < 12; ++i) {
    const int ld = i * 16 + rsub;
    const int d = (dbase + ld) & (PDIM - 1);
    const float av = a[d];
    const float4 vv = *(const float4*)(V + (size_t)d * PDIM + c0 + csub);
    vt[ld][csub + 0] = av * vv.x;
    vt[ld][csub + 1] = av * vv.y;
    vt[ld][csub + 2] = av * vv.z;
    vt[ld][csub + 3] = av * vv.w;
  }
  __syncthreads();
#pragma unroll
  for (int k = 0; k < 4; ++k) {
    const int ry = (t >> 3) + k * 32;
    const int cb = (t & 7) * 8;
    ushort_t pk[8];
#pragma unroll
    for (int j = 0; j < 8; ++j) {
      const int c = cb + j;
      pk[j] = f32_to_bf16_rne(vt[ry - c + 63][c]);
    }
    *(uint4*)(Wb + (size_t)(r0 + ry) * PDIM + c0 + cb) = *(const uint4*)pk;
  }
}

// ---------------- Kernel 3: bf16 MFMA GEMM, split-K x4, BM=BN=128 --------
// C_z = Xb[.,kq] * Wb^T[.,kq]; BM=128 BN=128 BK=64, KQ=1024.
// Grid (z=4, n=32, m=4) = 512 blocks -> 2 blocks/CU (co-residency probe).
// Partial traffic halves vs z=8: 16MB write + 16MB read.
__global__ __launch_bounds__(256, 3) void gemm_kernel(
    const ushort_t* __restrict__ Xb, const ushort_t* __restrict__ Wb,
    ushort_t* __restrict__ par) {
  constexpr int Kdim = 4096, KQ = 1024;
  __shared__ __align__(16) ushort_t As[128 * 64];
  __shared__ __align__(16) ushort_t Bs[128 * 64];
  const int tid = threadIdx.x;
  const int lane = tid & 63;
  const int w = tid >> 6;
  const int l15 = lane & 15;
  const int quad = lane >> 4;
  const int z = blockIdx.x;     // 0..3
  const int nblk = blockIdx.y;  // 0..31
  const int mblk = blockIdx.z;  // 0..3
  const int m0 = mblk * 128;
  const int n0 = nblk * 128;
  const int kbase = z * KQ;
  const int arow = lane >> 3;
  const int aslot = lane & 7;

  f32x4 acc[8][2];
#pragma unroll
  for (int mt = 0; mt < 8; ++mt)
#pragma unroll
    for (int nt = 0; nt < 2; ++nt) acc[mt][nt] = (f32x4){0.f, 0.f, 0.f, 0.f};

  for (int it = 0; it < KQ / 64; ++it) {
    const int k0 = kbase + it * 64;
#pragma unroll
    for (int s = w; s < 16; s += 4) {
      const int row = s * 8 + arow;
      const int j = aslot ^ (row & 7);
      async_cp16(Xb + (size_t)(m0 + row) * Kdim + k0 + j * 8,
                 (char*)As + (size_t)s * 1024);
      async_cp16(Wb + (size_t)(n0 + row) * Kdim + k0 + j * 8,
                 (char*)Bs + (size_t)s * 1024);
    }
    __syncthreads();
#pragma unroll
    for (int kk = 0; kk < 64; kk += 32) {
      const int cj = (kk >> 3) + quad;
      bf16x8 bfv[2];
#pragma unroll
      for (int nt = 0; nt < 2; ++nt) {
        const int row = w * 32 + nt * 16 + l15;
        bfv[nt] = *(const bf16x8*)&Bs[(row * 8 + (cj ^ (row & 7))) * 8];
      }
#pragma unroll
      for (int mt = 0; mt < 8; ++mt) {
        const int row = mt * 16 + l15;
        const bf16x8 af = *(const bf16x8*)&As[(row * 8 + (cj ^ (row & 7))) * 8];
        acc[mt][0] = __builtin_amdgcn_mfma_f32_16x16x32_bf16(af, bfv[0],
                                                             acc[mt][0], 0, 0, 0);
        acc[mt][1] = __builtin_amdgcn_mfma_f32_16x16x32_bf16(af, bfv[1],
                                                             acc[mt][1], 0, 0, 0);
      }
    }
    __syncthreads();
  }
  // epilogue: bf16 partials in blocked order, 8B/lane coalesced.
  const int tile = nblk * 4 + mblk;  // 0..127
  ushort_t* pbase = par + ((size_t)z * 128 + tile) * 16384;
#pragma unroll
  for (int mt = 0; mt < 8; ++mt) {
#pragma unroll
    for (int nt = 0; nt < 2; ++nt) {
      const int slot = mt * 2 + nt;
      ushort4 o;
      o.x = f32_to_bf16_rne(acc[mt][nt][0]);
      o.y = f32_to_bf16_rne(acc[mt][nt][1]);
      o.z = f32_to_bf16_rne(acc[mt][nt][2]);
      o.w = f32_to_bf16_rne(acc[mt][nt][3]);
      *(ushort4*)(pbase + (size_t)(slot * 256 + tid) * 4) = o;
    }
  }
}

// ---------------- Kernel 4: sum 4 blocked bf16 partials -> row-major out --
// Grid = 128 tiles x 4 quarters (512 blocks, 2/CU); mirrors gemm geometry.
__global__ __launch_bounds__(256) void combine_kernel(
    const ushort_t* __restrict__ par, float* __restrict__ out) {
  const int tile = blockIdx.x >> 2;  // 0..127
  const int qh = blockIdx.x & 3;
  const int nblk = tile >> 2;
  const int mblk = tile & 3;
  const int m0 = mblk * 128;
  const int n0 = nblk * 128;
  const int tid = threadIdx.x;
  const int lane = tid & 63;
  const int w = tid >> 6;
  const int l15 = lane & 15;
  const int quad = lane >> 4;
#pragma unroll
  for (int ss = 0; ss < 4; ++ss) {
    const int slot = qh * 4 + ss;
    float s0 = 0.f, s1 = 0.f, s2 = 0.f, s3 = 0.f;
#pragma unroll
    for (int z = 0; z < 4; ++z) {
      const ushort4 v = *(const ushort4*)(par +
          ((size_t)z * 128 + tile) * 16384 + (size_t)(slot * 256 + tid) * 4);
      s0 += bf16_to_f32(v.x);
      s1 += bf16_to_f32(v.y);
      s2 += bf16_to_f32(v.z);
      s3 += bf16_to_f32(v.w);
    }
    const int mt = slot >> 1;
    const int nt = slot & 1;
    const int mb = m0 + mt * 16 + quad * 4;
    const int n = n0 + w * 32 + nt * 16 + l15;
    out[(size_t)(mb + 0) * PDIM + n] = s0;
    out[(size_t)(mb + 1) * PDIM + n] = s1;
    out[(size_t)(mb + 2) * PDIM + n] = s2;
    out[(size_t)(mb + 3) * PDIM + n] = s3;
  }
}

extern "C" void kernel_launch(void* const* d_in, const int* in_sizes, int n_in,
                              void* d_out, int out_size, void* d_ws,
                              size_t ws_size, hipStream_t stream) {
  const float* x = (const float*)d_in[0];
  const float* V = (const float*)d_in[1];
  const float* alpha = (const float*)d_in[2];
  float* out = (float*)d_out;
  const int M = in_sizes[0] / PDIM;  // 512

  // ws: a(16KB) | Xb bf16 (4MB) | Wb bf16 (32MB) | partials bf16 4x4MB
  float* a_mask = (float*)d_ws;
  ushort_t* Xb = (ushort_t*)((char*)d_ws + 16 * 1024);
  ushort_t* Wb = Xb + (size_t)M * PDIM;
  ushort_t* par = Wb + (size_t)PDIM * PDIM;

  const int n4x = (M * PDIM) / 4;  // 524288
  // grid: [0] Dykstra | [1..2048] V->LLC prefetch | [2049..] x->bf16
  prep_kernel<<<1 + 2048 + (n4x + 255) / 256, 256, 0, stream>>>(
      alpha, a_mask, x, Xb, n4x, V);
  wmat_kernel<<<dim3(PDIM / 128, PDIM / 64), 256, 0, stream>>>(V, a_mask, Wb);
  gemm_kernel<<<dim3(4, PDIM / 128, M / 128), 256, 0, stream>>>(Xb, Wb, par);
  combine_kernel<<<512, 256, 0, stream>>>(par, out);
}